// Round 1
// 400.682 us; speedup vs baseline: 1.0394x; 1.0394x over previous
//
#include <hip/hip_runtime.h>
#include <math.h>

#define S_LEN 8192
#define BATCH 32
#define HDIM 256
#define DDIM 256
#define SCHUNK 1024     // s-rows per block (grid.x = 8, 256 blocks = 1/CU)
#define NSUB 16         // subtiles per block
#define TSUB 64         // s-rows per subtile
#define LDK 264         // padded LDS row stride (halfs): 528 B rows

typedef float f32x4 __attribute__((ext_vector_type(4)));
typedef __fp16 h16x2 __attribute__((ext_vector_type(2)));
typedef __fp16 h16x4 __attribute__((ext_vector_type(4)));
typedef _Float16 f16x8 __attribute__((ext_vector_type(8)));

static __device__ __forceinline__ float fast_tanh(float x) {
    // 1 - 2/(exp(2x)+1); monotone, NaN-free, saturates correctly at +-inf
    float e = __expf(2.0f * x);
    return 1.0f - 2.0f / (e + 1.0f);
}

// fp32x4 -> fp16 hi (RTZ) + fp16 lo residual, stored as 8B each
static __device__ __forceinline__ void cvt_store(f32x4 v, _Float16* ph, _Float16* pl) {
    h16x2 h0 = __builtin_amdgcn_cvt_pkrtz(v[0], v[1]);
    h16x2 h1 = __builtin_amdgcn_cvt_pkrtz(v[2], v[3]);
    h16x2 l0 = __builtin_amdgcn_cvt_pkrtz(v[0] - (float)h0[0], v[1] - (float)h0[1]);
    h16x2 l1 = __builtin_amdgcn_cvt_pkrtz(v[2] - (float)h1[0], v[3] - (float)h1[1]);
    h16x4 hi; hi[0] = h0[0]; hi[1] = h0[1]; hi[2] = h1[0]; hi[3] = h1[1];
    h16x4 lo; lo[0] = l0[0]; lo[1] = l0[1]; lo[2] = l1[0]; lo[3] = l1[1];
    *(h16x4*)ph = hi;
    *(h16x4*)pl = lo;
}

// ---------------------------------------------------------------------------
// Kernel 0: blocks [0,32): cin[b][h] = x[b]·W_in[h] + b_in[h] + b_ctx[h]
//           blocks [32,64): W_ctx -> fp16 (RNE), swizzled into MFMA A-frag
//           order: Wf[((ht*8+ks)*64 + lane)*8 + j] =
//              fp16(W_ctx[h = ht*16 + (lane&15)][d = ks*32 + (lane>>4)*8 + j])
// ---------------------------------------------------------------------------
__global__ void prep_kernel(const float* __restrict__ x,
                            const float* __restrict__ W_in,
                            const float* __restrict__ b_in,
                            const float* __restrict__ W_ctx,
                            const float* __restrict__ b_ctx,
                            float* __restrict__ cin,
                            _Float16* __restrict__ Wf) {
    __shared__ float xs[DDIM];
    const int bx = blockIdx.x;
    const int t  = threadIdx.x;
    if (bx < BATCH) {
        xs[t] = x[bx * DDIM + t];
        __syncthreads();
        const float* wr = W_in + t * DDIM;   // thread t owns output h = t
        float acc = b_in[t] + b_ctx[t];
        #pragma unroll 8
        for (int d = 0; d < DDIM; ++d) acc += xs[d] * wr[d];
        cin[bx * HDIM + t] = acc;
    } else {
        const int g  = (bx - BATCH) * 256 + t;   // 0..8191 fragment-groups
        const int ht = g >> 9;
        const int ks = (g >> 6) & 7;
        const int l  = g & 63;
        const int h  = ht * 16 + (l & 15);
        const int d0 = ks * 32 + (l >> 4) * 8;
        const float* src = W_ctx + h * DDIM + d0;
        f16x8 vh;
        #pragma unroll
        for (int j = 0; j < 8; ++j) vh[j] = (_Float16)src[j];   // v_cvt_f16_f32, RNE
        *(f16x8*)(Wf + (size_t)g * 8) = vh;
    }
}

// ---------------------------------------------------------------------------
// Kernel 1: C[h][s] = W·ctx^T. 512 threads / 8 waves; each wave owns TWO
// register-resident W h-tiles (32 h) x full 64-s subtile, so each LDS
// B-fragment read feeds 4 MFMAs (2 h-tiles x hi/lo) -> 32 FLOP/LDS-byte
// (above the 26.4 FLOP/B CU balance point), halving LDS read traffic vs
// the 16-wave/1-h-tile layout. acc initialized with cin[h] (free add).
// Epilogue: per-s reduce over h of tanh(acc)*V[h] -> att, out_mask.
// ---------------------------------------------------------------------------
__launch_bounds__(512, 2)
__global__ void att_kernel(const float* __restrict__ context,
                           const int* __restrict__ mask,
                           const float* __restrict__ cin,
                           const float* __restrict__ V,
                           const _Float16* __restrict__ Wf,
                           float* __restrict__ att,
                           float* __restrict__ out_mask) {
    __shared__ __align__(16) _Float16 a_hi[2][TSUB * LDK];   // 2 x 33792 B
    __shared__ __align__(16) _Float16 a_lo[2][TSUB * LDK];   // 2 x 33792 B
    __shared__ float att_part[2][8][TSUB];                   // 4 KB

    const int schunk = blockIdx.x;   // 0..7
    const int b      = blockIdx.y;   // 0..31
    const int t      = threadIdx.x;  // 0..511
    const int w      = t >> 6;       // wave 0..7 -> h in [w*32, w*32+32)
    const int l      = t & 63;
    const int lane16 = l & 15;
    const int q      = l >> 4;

    // W A-fragments for 2 h-tiles, register-resident (64 VGPRs)
    f16x8 wfrag[2][8];
    #pragma unroll
    for (int ht = 0; ht < 2; ++ht)
        #pragma unroll
        for (int ks = 0; ks < 8; ++ks)
            wfrag[ht][ks] = *(const f16x8*)(Wf + (size_t)(((w * 2 + ht) * 8 + ks) * 64 + l) * 8);

    // per-lane cin/V for epilogue rows: h = (w*2+ht)*16 + q*4 + r
    f32x4 cinr4[2], vr4[2];
    #pragma unroll
    for (int ht = 0; ht < 2; ++ht)
        #pragma unroll
        for (int r = 0; r < 4; ++r) {
            int h = (w * 2 + ht) * 16 + q * 4 + r;
            cinr4[ht][r] = cin[b * HDIM + h];
            vr4[ht][r]   = V[h];
        }

    const float* cbase = context + ((size_t)b * S_LEN + (size_t)schunk * SCHUNK) * DDIM;

    // ---- stage subtile 0 into buf 0 ----
    #pragma unroll
    for (int i = 0; i < 8; ++i) {
        int f = i * 512 + t, row = f >> 6, c4 = f & 63;
        f32x4 v = *(const f32x4*)(cbase + row * DDIM + c4 * 4);   // coalesced 16B/lane
        cvt_store(v, &a_hi[0][row * LDK + c4 * 4], &a_lo[0][row * LDK + c4 * 4]);
    }
    __syncthreads();

    for (int it = 0; it < NSUB; ++it) {
        const int cur = it & 1;
        const bool pre = (it + 1 < NSUB);

        // issue next subtile's global loads early (hidden under MFMA)
        f32x4 pf[8];
        if (pre) {
            const float* nb = cbase + (size_t)(it + 1) * TSUB * DDIM;
            #pragma unroll
            for (int i = 0; i < 8; ++i) {
                int f = i * 512 + t, row = f >> 6, c4 = f & 63;
                pf[i] = *(const f32x4*)(nb + row * DDIM + c4 * 4);
            }
        }

        // ---- MFMA: acc[ht][nt] (16 h x 16 s per tile), 2-pass hi/lo ----
        // acc initialized with cin[h]: folds the broadcast add for free.
        f32x4 acc[2][4];
        #pragma unroll
        for (int ht = 0; ht < 2; ++ht)
            #pragma unroll
            for (int nt = 0; nt < 4; ++nt) acc[ht][nt] = cinr4[ht];
        #pragma unroll
        for (int ks = 0; ks < 8; ++ks) {
            #pragma unroll
            for (int nt = 0; nt < 4; ++nt) {
                int o = (nt * 16 + lane16) * LDK + ks * 32 + q * 8;
                f16x8 bh = *(const f16x8*)(&a_hi[cur][o]);   // ds_read_b128
                f16x8 bl = *(const f16x8*)(&a_lo[cur][o]);
                #pragma unroll
                for (int ht = 0; ht < 2; ++ht) {
                    acc[ht][nt] = __builtin_amdgcn_mfma_f32_16x16x32_f16(wfrag[ht][ks], bh, acc[ht][nt], 0, 0, 0);
                    acc[ht][nt] = __builtin_amdgcn_mfma_f32_16x16x32_f16(wfrag[ht][ks], bl, acc[ht][nt], 0, 0, 0);
                }
            }
        }

        // ---- epilogue: C/D row = h (quad*4+reg), col = s (lane16) ----
        #pragma unroll
        for (int nt = 0; nt < 4; ++nt) {
            float p = 0.f;
            #pragma unroll
            for (int ht = 0; ht < 2; ++ht)
                #pragma unroll
                for (int r = 0; r < 4; ++r)
                    p += fast_tanh(acc[ht][nt][r]) * vr4[ht][r];
            p += __shfl_xor(p, 16);     // reduce over quads (h groups)
            p += __shfl_xor(p, 32);
            if (l < 16) att_part[cur][w][nt * 16 + l] = p;
        }

        // ---- convert + store next subtile into buf cur^1 ----
        if (pre) {
            #pragma unroll
            for (int i = 0; i < 8; ++i) {
                int f = i * 512 + t, row = f >> 6, c4 = f & 63;
                cvt_store(pf[i], &a_hi[cur ^ 1][row * LDK + c4 * 4],
                                 &a_lo[cur ^ 1][row * LDK + c4 * 4]);
            }
        }
        __syncthreads();

        // ---- finalize this subtile's 64 s-values ----
        if (t < TSUB) {
            float a = 0.f;
            #pragma unroll
            for (int ww = 0; ww < 8; ++ww) a += att_part[cur][ww][t];
            a = 10.0f * fast_tanh(a);
            int s  = schunk * SCHUNK + it * TSUB + t;
            int mk = mask[b * S_LEN + s];
            att[(size_t)b * S_LEN + s]      = mk ? a : -INFINITY;
            out_mask[(size_t)b * S_LEN + s] = mk ? 1.0f : 0.0f;
        }
    }
}

// ---------------------------------------------------------------------------
// Kernel 2: per-b argmax (first-index ties, like jnp.argmax) + p = 1/sum(exp)
// out layout: [0,32) indices as float, [32,64) p, [64,...) mask (written above)
// ---------------------------------------------------------------------------
__global__ void reduce_kernel(const float* __restrict__ att,
                              float* __restrict__ out) {
    __shared__ float smax[1024];
    __shared__ int   sidx[1024];
    const int b = blockIdx.x;
    const int t = threadIdx.x;
    const float* row = att + (size_t)b * S_LEN;

    float best = -INFINITY;
    int   bid  = 0x7fffffff;
    for (int s = t; s < S_LEN; s += 1024) {
        float v = row[s];
        if (v > best) { best = v; bid = s; }   // ascending s -> first index within thread
    }
    smax[t] = best; sidx[t] = bid;
    __syncthreads();
    for (int off = 512; off > 0; off >>= 1) {
        if (t < off) {
            float ov = smax[t + off]; int oi = sidx[t + off];
            if (ov > smax[t] || (ov == smax[t] && oi < sidx[t])) { smax[t] = ov; sidx[t] = oi; }
        }
        __syncthreads();
    }
    const float mx = smax[0];
    const int   ix = sidx[0];
    __syncthreads();

    float sum = 0.f;
    for (int s = t; s < S_LEN; s += 1024)
        sum += __expf(row[s] - mx);            // masked -inf -> exp -> 0
    smax[t] = sum;
    __syncthreads();
    for (int off = 512; off > 0; off >>= 1) {
        if (t < off) smax[t] += smax[t + off];
        __syncthreads();
    }
    if (t == 0) {
        out[b]         = (float)ix;
        out[BATCH + b] = 1.0f / smax[0];
    }
}

// ---------------------------------------------------------------------------
extern "C" void kernel_launch(void* const* d_in, const int* in_sizes, int n_in,
                              void* d_out, int out_size, void* d_ws, size_t ws_size,
                              hipStream_t stream) {
    const float* x       = (const float*)d_in[0];
    const float* context = (const float*)d_in[1];
    const int*   mask    = (const int*)d_in[2];
    const float* W_in    = (const float*)d_in[3];
    const float* b_in    = (const float*)d_in[4];
    const float* W_ctx   = (const float*)d_in[5];
    const float* b_ctx   = (const float*)d_in[6];
    const float* V       = (const float*)d_in[7];
    float* out = (float*)d_out;

    char* ws = (char*)d_ws;
    float*    cin = (float*)ws;                       // 32 KB
    _Float16* Wf  = (_Float16*)(ws + 32 * 1024);      // 128 KB
    float*    att = (float*)(ws + 160 * 1024);        // 1 MB

    float* out_mask = out + 64;

    prep_kernel<<<64, 256, 0, stream>>>(x, W_in, b_in, W_ctx, b_ctx, cin, Wf);
    dim3 grid(S_LEN / SCHUNK, BATCH);                 // 8 x 32 = 256 blocks
    att_kernel<<<grid, 512, 0, stream>>>(context, mask, cin, V, Wf, att, out_mask);
    reduce_kernel<<<BATCH, 1024, 0, stream>>>(att, out);
}

// Round 2
// 393.601 us; speedup vs baseline: 1.0581x; 1.0180x over previous
//
#include <hip/hip_runtime.h>
#include <math.h>

#define S_LEN 8192
#define BATCH 32
#define HDIM 256
#define DDIM 256
#define SCHUNK 1024     // s-rows per block (grid.x = 8, 256 blocks = 1/CU)
#define NSUB 16         // subtiles per block
#define TSUB 64         // s-rows per subtile
#define LDK 264         // padded LDS row stride (halfs): 528 B rows

typedef float f32x4 __attribute__((ext_vector_type(4)));
typedef __fp16 h16x2 __attribute__((ext_vector_type(2)));
typedef __fp16 h16x4 __attribute__((ext_vector_type(4)));
typedef _Float16 f16x8 __attribute__((ext_vector_type(8)));

static __device__ __forceinline__ float fast_tanh(float x) {
    // 1 - 2/(exp(2x)+1); monotone, NaN-free, saturates correctly at +-inf
    float e = __expf(2.0f * x);
    return 1.0f - 2.0f / (e + 1.0f);
}

// fp32x4 -> fp16 hi (RTZ) + fp16 lo residual, stored as 8B each
static __device__ __forceinline__ void cvt_store(f32x4 v, _Float16* ph, _Float16* pl) {
    h16x2 h0 = __builtin_amdgcn_cvt_pkrtz(v[0], v[1]);
    h16x2 h1 = __builtin_amdgcn_cvt_pkrtz(v[2], v[3]);
    h16x2 l0 = __builtin_amdgcn_cvt_pkrtz(v[0] - (float)h0[0], v[1] - (float)h0[1]);
    h16x2 l1 = __builtin_amdgcn_cvt_pkrtz(v[2] - (float)h1[0], v[3] - (float)h1[1]);
    h16x4 hi; hi[0] = h0[0]; hi[1] = h0[1]; hi[2] = h1[0]; hi[3] = h1[1];
    h16x4 lo; lo[0] = l0[0]; lo[1] = l0[1]; lo[2] = l1[0]; lo[3] = l1[1];
    *(h16x4*)ph = hi;
    *(h16x4*)pl = lo;
}

// ---------------------------------------------------------------------------
// Kernel 0: blocks [0,32): cin[b][h] = x[b]·W_in[h] + b_in[h] + b_ctx[h]
//           (+ thread 0 zeroes batch-b's atomic finalize slots)
//           blocks [32,64): W_ctx -> fp16 (RNE), swizzled into MFMA A-frag
//           order: Wf[((ht*8+ks)*64 + lane)*8 + j] =
//              fp16(W_ctx[h = ht*16 + (lane&15)][d = ks*32 + (lane>>4)*8 + j])
// ---------------------------------------------------------------------------
__global__ void prep_kernel(const float* __restrict__ x,
                            const float* __restrict__ W_in,
                            const float* __restrict__ b_in,
                            const float* __restrict__ W_ctx,
                            const float* __restrict__ b_ctx,
                            float* __restrict__ cin,
                            _Float16* __restrict__ Wf,
                            unsigned long long* __restrict__ pmax,
                            float* __restrict__ psum,
                            int* __restrict__ pcnt) {
    __shared__ float xs[DDIM];
    const int bx = blockIdx.x;
    const int t  = threadIdx.x;
    if (bx < BATCH) {
        if (t == 0) {            // reset finalize slots for this batch row
            pmax[bx] = 0ull;     // any real packed score > 0 (see att pack)
            psum[bx] = 0.0f;
            pcnt[bx] = 0;
        }
        xs[t] = x[bx * DDIM + t];
        __syncthreads();
        const float* wr = W_in + t * DDIM;   // thread t owns output h = t
        float acc = b_in[t] + b_ctx[t];
        #pragma unroll 8
        for (int d = 0; d < DDIM; ++d) acc += xs[d] * wr[d];
        cin[bx * HDIM + t] = acc;
    } else {
        const int g  = (bx - BATCH) * 256 + t;   // 0..8191 fragment-groups
        const int ht = g >> 9;
        const int ks = (g >> 6) & 7;
        const int l  = g & 63;
        const int h  = ht * 16 + (l & 15);
        const int d0 = ks * 32 + (l >> 4) * 8;
        const float* src = W_ctx + h * DDIM + d0;
        f16x8 vh;
        #pragma unroll
        for (int j = 0; j < 8; ++j) vh[j] = (_Float16)src[j];   // v_cvt_f16_f32, RNE
        *(f16x8*)(Wf + (size_t)g * 8) = vh;
    }
}

// ---------------------------------------------------------------------------
// Kernel 1: C[h][s] = W·ctx^T with fused finalize. 512 threads / 8 waves;
// each wave owns TWO register-resident W h-tiles (32 h) x 64-s subtile.
// acc initialized with cin[h]. Epilogue reduces tanh(acc)*V over h -> att[s].
// Since att = 10*tanh(.) is in [-10,10], softmax needs no global max pass:
// each block accumulates (max, first-argmax, sum exp(att-10)) over its 1024 s
// in wave-0 registers, then publishes via device-scope atomics; the 8th
// arriving block per batch row computes p = exp(max-10)/sum and writes out.
// This deletes the reduce kernel, one launch gap, and the 3 MB att roundtrip.
// ---------------------------------------------------------------------------
__launch_bounds__(512, 2)
__global__ void att_kernel(const float* __restrict__ context,
                           const int* __restrict__ mask,
                           const float* __restrict__ cin,
                           const float* __restrict__ V,
                           const _Float16* __restrict__ Wf,
                           float* __restrict__ out,
                           float* __restrict__ out_mask,
                           unsigned long long* __restrict__ pmax,
                           float* __restrict__ psum,
                           int* __restrict__ pcnt) {
    __shared__ __align__(16) _Float16 a_hi[2][TSUB * LDK];   // 2 x 33792 B
    __shared__ __align__(16) _Float16 a_lo[2][TSUB * LDK];   // 2 x 33792 B
    __shared__ float att_part[2][8][TSUB];                   // 4 KB

    const int schunk = blockIdx.x;   // 0..7
    const int b      = blockIdx.y;   // 0..31
    const int t      = threadIdx.x;  // 0..511
    const int w      = t >> 6;       // wave 0..7 -> h in [w*32, w*32+32)
    const int l      = t & 63;
    const int lane16 = l & 15;
    const int q      = l >> 4;

    // W A-fragments for 2 h-tiles, register-resident (64 VGPRs)
    f16x8 wfrag[2][8];
    #pragma unroll
    for (int ht = 0; ht < 2; ++ht)
        #pragma unroll
        for (int ks = 0; ks < 8; ++ks)
            wfrag[ht][ks] = *(const f16x8*)(Wf + (size_t)(((w * 2 + ht) * 8 + ks) * 64 + l) * 8);

    // per-lane cin/V for epilogue rows: h = (w*2+ht)*16 + q*4 + r
    f32x4 cinr4[2], vr4[2];
    #pragma unroll
    for (int ht = 0; ht < 2; ++ht)
        #pragma unroll
        for (int r = 0; r < 4; ++r) {
            int h = (w * 2 + ht) * 16 + q * 4 + r;
            cinr4[ht][r] = cin[b * HDIM + h];
            vr4[ht][r]   = V[h];
        }

    const float* cbase = context + ((size_t)b * S_LEN + (size_t)schunk * SCHUNK) * DDIM;

    // block-local finalize state (live in wave 0 / threads 0..63)
    float best = -INFINITY;
    int   bid  = 0x7fffffff;
    float sume = 0.0f;

    // ---- stage subtile 0 into buf 0 ----
    #pragma unroll
    for (int i = 0; i < 8; ++i) {
        int f = i * 512 + t, row = f >> 6, c4 = f & 63;
        f32x4 v = *(const f32x4*)(cbase + row * DDIM + c4 * 4);   // coalesced 16B/lane
        cvt_store(v, &a_hi[0][row * LDK + c4 * 4], &a_lo[0][row * LDK + c4 * 4]);
    }
    __syncthreads();

    for (int it = 0; it < NSUB; ++it) {
        const int cur = it & 1;
        const bool pre = (it + 1 < NSUB);

        // issue next subtile's global loads early (hidden under MFMA)
        f32x4 pf[8];
        if (pre) {
            const float* nb = cbase + (size_t)(it + 1) * TSUB * DDIM;
            #pragma unroll
            for (int i = 0; i < 8; ++i) {
                int f = i * 512 + t, row = f >> 6, c4 = f & 63;
                pf[i] = *(const f32x4*)(nb + row * DDIM + c4 * 4);
            }
        }

        // ---- MFMA: acc[ht][nt] (16 h x 16 s per tile), 2-pass hi/lo ----
        f32x4 acc[2][4];
        #pragma unroll
        for (int ht = 0; ht < 2; ++ht)
            #pragma unroll
            for (int nt = 0; nt < 4; ++nt) acc[ht][nt] = cinr4[ht];
        #pragma unroll
        for (int ks = 0; ks < 8; ++ks) {
            #pragma unroll
            for (int nt = 0; nt < 4; ++nt) {
                int o = (nt * 16 + lane16) * LDK + ks * 32 + q * 8;
                f16x8 bh = *(const f16x8*)(&a_hi[cur][o]);   // ds_read_b128
                f16x8 bl = *(const f16x8*)(&a_lo[cur][o]);
                #pragma unroll
                for (int ht = 0; ht < 2; ++ht) {
                    acc[ht][nt] = __builtin_amdgcn_mfma_f32_16x16x32_f16(wfrag[ht][ks], bh, acc[ht][nt], 0, 0, 0);
                    acc[ht][nt] = __builtin_amdgcn_mfma_f32_16x16x32_f16(wfrag[ht][ks], bl, acc[ht][nt], 0, 0, 0);
                }
            }
        }

        // ---- epilogue: C/D row = h (quad*4+reg), col = s (lane16) ----
        #pragma unroll
        for (int nt = 0; nt < 4; ++nt) {
            float p = 0.f;
            #pragma unroll
            for (int ht = 0; ht < 2; ++ht)
                #pragma unroll
                for (int r = 0; r < 4; ++r)
                    p += fast_tanh(acc[ht][nt][r]) * vr4[ht][r];
            p += __shfl_xor(p, 16);     // reduce over quads (h groups)
            p += __shfl_xor(p, 32);
            if (l < 16) att_part[cur][w][nt * 16 + l] = p;
        }

        // ---- convert + store next subtile into buf cur^1 ----
        if (pre) {
            #pragma unroll
            for (int i = 0; i < 8; ++i) {
                int f = i * 512 + t, row = f >> 6, c4 = f & 63;
                cvt_store(pf[i], &a_hi[cur ^ 1][row * LDK + c4 * 4],
                                 &a_lo[cur ^ 1][row * LDK + c4 * 4]);
            }
        }
        __syncthreads();

        // ---- finalize this subtile's 64 s-values (wave 0 only) ----
        if (t < TSUB) {
            float a = 0.f;
            #pragma unroll
            for (int ww = 0; ww < 8; ++ww) a += att_part[cur][ww][t];
            a = 10.0f * fast_tanh(a);
            int s  = schunk * SCHUNK + it * TSUB + t;
            int mk = mask[b * S_LEN + s];
            out_mask[(size_t)b * S_LEN + s] = mk ? 1.0f : 0.0f;
            if (mk) {
                if (a > best) { best = a; bid = s; }   // ascending s -> first index
                sume += __expf(a - 10.0f);             // bounded: a in [-10,10]
            }
        }
    }

    // ---- block reduce (wave 0) + cross-block publish ----
    if (w == 0) {
        #pragma unroll
        for (int off = 32; off > 0; off >>= 1) {
            float ov = __shfl_xor(best, off);
            int   oi = __shfl_xor(bid, off);
            float os = __shfl_xor(sume, off);
            sume += os;
            if (ov > best || (ov == best && oi < bid)) { best = ov; bid = oi; }
        }
        if (l == 0) {
            // pack: orderable float bits in high word, inverted index low word
            unsigned ub = __float_as_uint(best);
            ub = (ub & 0x80000000u) ? ~ub : (ub | 0x80000000u);
            unsigned long long pk =
                ((unsigned long long)ub << 32) | (unsigned long long)(0xFFFFFFFFu - (unsigned)bid);
            atomicMax(&pmax[b], pk);
            atomicAdd(&psum[b], sume);
            __threadfence();
            int old = atomicAdd(&pcnt[b], 1);
            if (old == 7) {                     // last of 8 blocks for this b
                __threadfence();
                unsigned long long m = atomicMax(&pmax[b], 0ull);   // coherent read
                float ssum = atomicAdd(&psum[b], 0.0f);             // coherent read
                unsigned mb = (unsigned)(m >> 32);
                float mv = (mb & 0x80000000u) ? __uint_as_float(mb ^ 0x80000000u)
                                              : __uint_as_float(~mb);
                int idx = (int)(0xFFFFFFFFu - (unsigned)(m & 0xFFFFFFFFull));
                out[b]         = (float)idx;
                out[BATCH + b] = __expf(mv - 10.0f) / ssum;
            }
        }
    }
}

// ---------------------------------------------------------------------------
extern "C" void kernel_launch(void* const* d_in, const int* in_sizes, int n_in,
                              void* d_out, int out_size, void* d_ws, size_t ws_size,
                              hipStream_t stream) {
    const float* x       = (const float*)d_in[0];
    const float* context = (const float*)d_in[1];
    const int*   mask    = (const int*)d_in[2];
    const float* W_in    = (const float*)d_in[3];
    const float* b_in    = (const float*)d_in[4];
    const float* W_ctx   = (const float*)d_in[5];
    const float* b_ctx   = (const float*)d_in[6];
    const float* V       = (const float*)d_in[7];
    float* out = (float*)d_out;

    char* ws = (char*)d_ws;
    float*              cin  = (float*)ws;                         // 32 KB
    _Float16*           Wf   = (_Float16*)(ws + 32 * 1024);        // 128 KB
    unsigned long long* pmax = (unsigned long long*)(ws + 160 * 1024);  // 256 B
    float*              psum = (float*)(ws + 160 * 1024 + 256);    // 128 B
    int*                pcnt = (int*)(ws + 160 * 1024 + 384);      // 128 B

    float* out_mask = out + 64;

    prep_kernel<<<64, 256, 0, stream>>>(x, W_in, b_in, W_ctx, b_ctx, cin, Wf,
                                        pmax, psum, pcnt);
    dim3 grid(S_LEN / SCHUNK, BATCH);                 // 8 x 32 = 256 blocks
    att_kernel<<<grid, 512, 0, stream>>>(context, mask, cin, V, Wf,
                                         out, out_mask, pmax, psum, pcnt);
}